// Round 5
// baseline (16372.998 us; speedup 1.0000x reference)
//
#include <hip/hip_runtime.h>

// ---------------------------------------------------------------------------
// RevRNN persistent kernel, round 8 = round 7 + forced x prefetch + early poll.
// Round 7 (14.76 ms, passed): self-validating tagged u64 exchange words,
// fire-and-forget publish, merged poll+load, per-wave K-slices + LDS.
// Evidence: VGPR_Count=156 << static demand (~290) => compiler SANK the
// xf[16] prefetch loads to their use => ~900cy HBM x-wait exposed on the
// straggler's critical path; first poll sample also issued late.
// Changes (skeleton, protocol, tags, numerics all unchanged):
// 1. x staged via __builtin_amdgcn_global_load_lds into double-buffered LDS
//    (side-effecting intrinsic: CANNOT be sunk; zero VGPR). Issued at
//    phase-A start for t+1; vmcnt(0) in TAIL-A pre-publish (loads ~850cy
//    old there -> near-free); A's end barrier makes LDS visible to all
//    waves before A(t+1) reads. Frees 64 VGPR, de-duplicates 4x per-wave
//    x fetches. Rows padded to 262 f32 (<=4-way bank conflict, float2 reads).
// 2. Early poll issue: the 12 poll loads issue at phase start (pinned by a
//    compiler memory barrier), checked after the x-MFMA block -> a
//    late-arriving WG saves a full ~700cy detect round trip.
// - Sticky 'alive' guard -> loud wrong answer instead of hang.
// ---------------------------------------------------------------------------

#define T_TOT 2056
#define S_SEQ 2048

typedef _Float16 f16x8 __attribute__((ext_vector_type(8)));
typedef float f32x4 __attribute__((ext_vector_type(4)));

// exchange arrays: static device globals (no workspace-size dependency)
__device__ unsigned long long g_st0[8192];  // [64 rows][128 colpair cells]
__device__ unsigned long long g_st1[8192];
__device__ unsigned long long g_pa0[1024];  // [256 ocol][4 b-groups]
__device__ unsigned long long g_pa1[1024];

__global__ void init_ws() {
  const int i = (int)blockIdx.x * 256 + (int)threadIdx.x;  // 8192 threads
  g_st0[i] = 0ull;
  g_st1[i] = 0ull;
  if (i < 1024) { g_pa0[i] = 0ull; g_pa1[i] = 0ull; }
}

#define AL(P) __hip_atomic_load((P), __ATOMIC_RELAXED, __HIP_MEMORY_SCOPE_AGENT)
#define AS(P, V)                                                               \
  __hip_atomic_store((P), (V), __ATOMIC_RELAXED, __HIP_MEMORY_SCOPE_AGENT)

// issue the 12 poll loads NOW (early); memory barrier pins the issue point.
#define PHASE_BEGIN(SIN, PIN)                                                  \
    const unsigned long long* pp_ = (PIN) + 4 * tid;                           \
    const unsigned long long* sp_ =                                            \
        (SIN) + (size_t)(16 * b + n) * 128 + (2 * wv) * 16 + kq * 4;           \
    unsigned long long q0_ = AL(pp_ + 0), q1_ = AL(pp_ + 1),                   \
                       q2_ = AL(pp_ + 2), q3_ = AL(pp_ + 3);                   \
    unsigned long long s0_ = AL(sp_ + 0), s1_ = AL(sp_ + 1),                   \
                       s2_ = AL(sp_ + 2), s3_ = AL(sp_ + 3),                   \
                       s4_ = AL(sp_ + 16), s5_ = AL(sp_ + 17),                 \
                       s6_ = AL(sp_ + 18), s7_ = AL(sp_ + 19);                 \
    asm volatile("" ::: "memory");

// spin (first check uses early loads) -> LDS -> barrier -> centered MFMA ->
// gate -> [stage vmcnt] -> tagged publish (fire-and-forget) -> end barrier.
#define PHASE_END(TAGIN, WS, SOUT, POUT, TAGOUT, RAW, DO_VM)                   \
  {                                                                            \
    const unsigned tg_ = (unsigned)(TAGIN);                                    \
    int it_ = 0;                                                               \
    for (;;) {                                                                 \
      const unsigned ok_ =                                                     \
          ((unsigned)(q0_ >> 32) >= tg_) & ((unsigned)(q1_ >> 32) >= tg_) &    \
          ((unsigned)(q2_ >> 32) >= tg_) & ((unsigned)(q3_ >> 32) >= tg_) &    \
          ((unsigned)(s0_ >> 32) >= tg_) & ((unsigned)(s1_ >> 32) >= tg_) &    \
          ((unsigned)(s2_ >> 32) >= tg_) & ((unsigned)(s3_ >> 32) >= tg_) &    \
          ((unsigned)(s4_ >> 32) >= tg_) & ((unsigned)(s5_ >> 32) >= tg_) &    \
          ((unsigned)(s6_ >> 32) >= tg_) & ((unsigned)(s7_ >> 32) >= tg_);     \
      if (ok_) break;                                                          \
      if (!alive || ++it_ > (1 << 17)) { alive = 0; break; }                   \
      q0_ = AL(pp_ + 0); q1_ = AL(pp_ + 1);                                    \
      q2_ = AL(pp_ + 2); q3_ = AL(pp_ + 3);                                    \
      s0_ = AL(sp_ + 0); s1_ = AL(sp_ + 1);                                    \
      s2_ = AL(sp_ + 2); s3_ = AL(sp_ + 3);                                    \
      s4_ = AL(sp_ + 16); s5_ = AL(sp_ + 17);                                  \
      s6_ = AL(sp_ + 18); s7_ = AL(sp_ + 19);                                  \
    }                                                                          \
    const float mean_ = (__uint_as_float((unsigned)q0_) +                      \
                         __uint_as_float((unsigned)q1_) +                      \
                         __uint_as_float((unsigned)q2_) +                      \
                         __uint_as_float((unsigned)q3_)) * 0.015625f;          \
    mean_h[tid] = (_Float16)mean_;                                             \
    {                                                                          \
      unsigned long long* lp_ =                                                \
          (unsigned long long*)&lds_s[n][(2 * wv) * 16 + kq * 4];              \
      lp_[0] = ((unsigned long long)(unsigned)s1_ << 32) | (unsigned)s0_;      \
      lp_[1] = ((unsigned long long)(unsigned)s3_ << 32) | (unsigned)s2_;      \
      lp_[8] = ((unsigned long long)(unsigned)s5_ << 32) | (unsigned)s4_;      \
      lp_[9] = ((unsigned long long)(unsigned)s7_ << 32) | (unsigned)s6_;      \
    }                                                                          \
    __syncthreads();                                                           \
    _Pragma("unroll")                                                          \
    for (int kk = 0; kk < 8; ++kk) {                                           \
      const f16x8 sv_ = *(const f16x8*)&lds_s[n][kk * 16 + kq * 4];            \
      const f16x8 mv_ = *(const f16x8*)&mean_h[kk * 32 + kq * 8];              \
      if (kk & 1)                                                              \
        acc1 = __builtin_amdgcn_mfma_f32_16x16x32_f16(sv_ - mv_, (WS)[kk],     \
                                                      acc1, 0, 0, 0);          \
      else                                                                     \
        acc0 = __builtin_amdgcn_mfma_f32_16x16x32_f16(sv_ - mv_, (WS)[kk],     \
                                                      acc0, 0, 0, 0);          \
    }                                                                          \
    float nv_[4], ssum_ = 0.f;                                                 \
    _Pragma("unroll")                                                          \
    for (int r = 0; r < 4; ++r) {                                              \
      const float z = acc0[r] + acc1[r];                                       \
      const float p = __shfl_xor(z, 8);                                        \
      const float z0 = (n < 8) ? z : p;                                        \
      const float z1 = (n < 8) ? p : z;                                        \
      /* branch-free tanh: clamp +-10, (e-1)/(e+1); err << f16 quantization */ \
      const float z1c = fminf(fmaxf(z1, -10.f), 10.f);                         \
      const float e2 = __expf(2.f * z1c);                                      \
      const float th = (e2 - 1.f) * __builtin_amdgcn_rcpf(e2 + 1.f);           \
      const float cv = fminf(fmaxf(z0, 0.f), 6.f) * th;                        \
      const float o = ((RAW)[r] + cv) * 0.5f;                                  \
      (RAW)[r] = o; nv_[r] = o; ssum_ += o;                                    \
    }                                                                          \
    ssum_ += __shfl_xor(ssum_, 16);                                            \
    ssum_ += __shfl_xor(ssum_, 32);                                            \
    if (DO_VM) /* stage loads issued this phase are ~850cy old: near-free */   \
      asm volatile("s_waitcnt vmcnt(0)" ::: "memory");                         \
    _Pragma("unroll")                                                          \
    for (int r = 0; r < 4; ++r) {                                              \
      union { _Float16 h; unsigned short u; } hb_;                             \
      hb_.h = (_Float16)nv_[r];                                                \
      const unsigned pr_ = (unsigned)__shfl_xor((int)hb_.u, 1) & 0xFFFFu;      \
      if ((n & 1) == 0 && n < 8) {                                             \
        const unsigned dw_ = (unsigned)hb_.u | (pr_ << 16);                    \
        AS((SOUT) + (size_t)(16 * b + kq * 4 + r) * 128 + (ocol >> 1),         \
           ((unsigned long long)(unsigned)(TAGOUT) << 32) |                    \
               (unsigned long long)dw_);                                       \
      }                                                                        \
    }                                                                          \
    if (kq == 0 && n < 8)                                                      \
      AS((POUT) + (size_t)ocol * 4 + b,                                        \
         ((unsigned long long)(unsigned)(TAGOUT) << 32) |                      \
             (unsigned long long)__float_as_uint(ssum_));                      \
    __syncthreads(); /* lds_s/mean_h epoch + x-stage visibility */             \
  }

// stage x(t=TT) into xs[TT&1]: wave wv stages rows wv*4..wv*4+3; one
// global_load_lds per row (64 lanes x 16B = full 1024B row). Zero VGPRs,
// cannot be sunk by the compiler (side-effecting intrinsic).
#define STAGE_X(TT)                                                            \
  if ((TT) < S_SEQ) {                                                          \
    const int bf_ = (TT) & 1;                                                  \
    _Pragma("unroll")                                                          \
    for (int j_ = 0; j_ < 4; ++j_) {                                           \
      const int row_ = wv * 4 + j_;                                            \
      const float* gs_ =                                                       \
          xg + ((size_t)(16 * b + row_) * S_SEQ + (TT)) * 256 + ln * 4;        \
      __builtin_amdgcn_global_load_lds(                                        \
          (const __attribute__((address_space(1))) unsigned*)gs_,              \
          (__attribute__((address_space(3))) unsigned*)&xs[bf_][row_][0],      \
          16, 0, 0);                                                           \
    }                                                                          \
  }

__launch_bounds__(256, 1)
__global__ void rnn_kernel(const float* __restrict__ xg,
                           const float* __restrict__ hs,
                           const float* __restrict__ W0,
                           const float* __restrict__ W1,
                           float* __restrict__ out) {
  const int wgid = (int)blockIdx.x;        // 0..31
  const int b = wgid & 3;                  // batch group: rows 16b..16b+15
  const int c = wgid >> 2;                 // col group: o-cols 32c..32c+31
  const int tid = (int)threadIdx.x;
  const int wv = tid >> 6;                 // wave 0..3
  const int ln = tid & 63;
  const int n = ln & 15;                   // packed col in tile / A-row
  const int kq = ln >> 4;                  // quad 0..3
  const int ocol = c * 32 + wv * 8 + (n & 7);      // owned output column
  const int wrow = (n < 8) ? ocol : (256 + ocol);  // packed W row (z0|z1)

  __shared__ __align__(16) unsigned lds_s[16][132];   // state payload, padded
  __shared__ __align__(16) _Float16 mean_h[256];
  __shared__ __align__(16) float xs[2][16][262];      // x stage, 262-padded

  // ---- preload W fragments (state part + x part) into registers ----
  f16x8 w0s[8], w0x[8], w1s[8], w1x[8];
  float w0pa, w0pb, w1pa, w1pb;
  {
    const float* r0 = W0 + (size_t)wrow * 514;
    const float* r1 = W1 + (size_t)wrow * 514;
#pragma unroll
    for (int kk = 0; kk < 8; ++kk) {
      const int k0 = kk * 32 + kq * 8;
      f16x8 a, bx, a1, bx1;
#pragma unroll
      for (int j = 0; j < 8; ++j) {
        a[j]   = (_Float16)r0[k0 + j];
        bx[j]  = (_Float16)r0[256 + k0 + j];
        a1[j]  = (_Float16)r1[k0 + j];
        bx1[j] = (_Float16)r1[256 + k0 + j];
      }
      w0s[kk] = a; w0x[kk] = bx; w1s[kk] = a1; w1x[kk] = bx1;
    }
    w0pa = r0[512]; w0pb = r0[513];
    w1pa = r1[512]; w1pb = r1[513];
  }

  // ---- raw recurrence state (fp32, register-resident) ----
  float raw0[4], raw1[4];
#pragma unroll
  for (int r = 0; r < 4; ++r) { raw0[r] = hs[ocol]; raw1[r] = hs[256 + ocol]; }

  int alive = 1;

  // ---- init publish: tagged uncentered h0 pairs + tagged partials, tag 1.
  {
    union { _Float16 h; unsigned short u; } e0, e1;
    e0.h = (_Float16)hs[ocol]; e1.h = (_Float16)hs[ocol + 1];
    const unsigned dw = (unsigned)e0.u | ((unsigned)e1.u << 16);
    if ((n & 1) == 0 && n < 8) {
#pragma unroll
      for (int r = 0; r < 4; ++r)
        AS(g_st0 + (size_t)(16 * b + kq * 4 + r) * 128 + (ocol >> 1),
           (1ull << 32) | (unsigned long long)dw);
    }
    if (kq == 0 && n < 8)
      AS(g_pa0 + (size_t)ocol * 4 + b,
         (1ull << 32) |
             (unsigned long long)__float_as_uint(16.f * hs[ocol]));
  }

  // ---- prologue: stage x(0) into xs[0] ----
  STAGE_X(0);
  asm volatile("s_waitcnt vmcnt(0)" ::: "memory");
  __syncthreads();

  f16x8 xa[8];
  for (int t = 0; t < T_TOT; ++t) {
    const float pe0 = (float)(t + 1);
    const float pe1 = (pe0 - 1028.5f) * (1.0f / 1028.5f);
    const int have_x = (t < S_SEQ);

    // ---------------- phase A: o1 = (h1 + calc(h0c, s, W0)) * 0.5 ----------
    {
      f32x4 acc0, acc1;
      const float pt = pe0 * w0pa + pe1 * w0pb;
      acc0[0] = pt; acc0[1] = pt; acc0[2] = pt; acc0[3] = pt;
      acc1[0] = 0.f; acc1[1] = 0.f; acc1[2] = 0.f; acc1[3] = 0.f;
      PHASE_BEGIN(g_st0, g_pa0);     // poll loads in flight during x work
      STAGE_X(t + 1);                // async x(t+1) -> LDS, zero VGPR
      if (have_x) {
        const float* xr = &xs[t & 1][n][0];
#pragma unroll
        for (int kk = 0; kk < 8; ++kk) {
          const float2 a0 = *(const float2*)(xr + kk * 32 + kq * 8);
          const float2 a1 = *(const float2*)(xr + kk * 32 + kq * 8 + 2);
          const float2 a2 = *(const float2*)(xr + kk * 32 + kq * 8 + 4);
          const float2 a3 = *(const float2*)(xr + kk * 32 + kq * 8 + 6);
          f16x8 af;
          af[0] = (_Float16)a0.x; af[1] = (_Float16)a0.y;
          af[2] = (_Float16)a1.x; af[3] = (_Float16)a1.y;
          af[4] = (_Float16)a2.x; af[5] = (_Float16)a2.y;
          af[6] = (_Float16)a3.x; af[7] = (_Float16)a3.y;
          xa[kk] = af;
          if (kk & 1)
            acc1 = __builtin_amdgcn_mfma_f32_16x16x32_f16(af, w0x[kk], acc1,
                                                          0, 0, 0);
          else
            acc0 = __builtin_amdgcn_mfma_f32_16x16x32_f16(af, w0x[kk], acc0,
                                                          0, 0, 0);
        }
      }
      PHASE_END(2 * t + 1, w0s, g_st1, g_pa1, 2 * t + 2, raw1, 1);
    }

    // ---------------- phase B: o0 = (h0 + calc(o1c, s, W1)) * 0.5 ----------
    {
      f32x4 acc0, acc1;
      const float pt = pe0 * w1pa + pe1 * w1pb;
      acc0[0] = pt; acc0[1] = pt; acc0[2] = pt; acc0[3] = pt;
      acc1[0] = 0.f; acc1[1] = 0.f; acc1[2] = 0.f; acc1[3] = 0.f;
      PHASE_BEGIN(g_st1, g_pa1);     // poll loads in flight during x-MFMAs
      if (have_x) {
#pragma unroll
        for (int kk = 0; kk < 8; ++kk) {
          if (kk & 1)
            acc1 = __builtin_amdgcn_mfma_f32_16x16x32_f16(xa[kk], w1x[kk],
                                                          acc1, 0, 0, 0);
          else
            acc0 = __builtin_amdgcn_mfma_f32_16x16x32_f16(xa[kk], w1x[kk],
                                                          acc0, 0, 0, 0);
        }
      }
      PHASE_END(2 * t + 2, w1s, g_st0, g_pa0, 2 * t + 3, raw0, 0);
    }
  }

  // ---- final h = [o0 | o1] fp32 ----
  if (n < 8) {
#pragma unroll
    for (int r = 0; r < 4; ++r) {
      const int row = 16 * b + kq * 4 + r;
      out[(size_t)row * 512 + ocol] = raw0[r];
      out[(size_t)row * 512 + 256 + ocol] = raw1[r];
    }
  }
}

#undef STAGE_X
#undef PHASE_END
#undef PHASE_BEGIN
#undef AS
#undef AL

extern "C" void kernel_launch(void* const* d_in, const int* in_sizes, int n_in,
                              void* d_out, int out_size, void* d_ws, size_t ws_size,
                              hipStream_t stream) {
  (void)in_sizes; (void)n_in; (void)out_size; (void)d_ws; (void)ws_size;
  const float* x  = (const float*)d_in[0];
  const float* hs = (const float*)d_in[1];
  const float* W0 = (const float*)d_in[2];
  const float* W1 = (const float*)d_in[3];
  float* out = (float*)d_out;

  // prologue kernel zeroes the tagged exchange globals (stream-ordered;
  // replayed per graph iteration -> tags reset each run). No workspace use.
  init_ws<<<dim3(32), dim3(256), 0, stream>>>();
  rnn_kernel<<<dim3(32), dim3(256), 0, stream>>>(x, hs, W0, W1, out);
}

// Round 7
// 16140.314 us; speedup vs baseline: 1.0144x; 1.0144x over previous
//
#include <hip/hip_runtime.h>

// ---------------------------------------------------------------------------
// RevRNN persistent kernel, round 10 = round 9 resubmit (infra-flake probe).
// Round 9 died with "container failed twice" and zero diagnostics (no
// compile error, no pytest output) -- same opaque symptom as round 6, whose
// protocol later PASSED in round 7. Line audit of r9 found no deterministic
// hang: barriers are WG-uniform, LDS epochs are barrier-separated, vmcnt
// accounting is conservative-correct, s_barrier with outstanding VMEM is
// HW-proven (learn_hip m194-m201), spin guard is sticky. Conclusion: infra.
// This round isolates that hypothesis: same kernel, spin guard 2^17->2^16.
//
// Structure (= r9): r8 skeleton (LDS x staging via global_load_lds, early
// poll issue) with HIP __syncthreads (which drains vmcnt(0): serialized the
// publish store-ack ~700-900cy and r8's stage-drain ~900cy) replaced by raw
// s_barrier + counted waits:
// - post-poll + A-end barriers: lgkmcnt(0) only; publish stores and stage
//   loads ride across in the background.
// - B-end barrier: lgkmcnt(0) vmcnt(5): drains stage loads + A-stores
//   (old, ~free), never the 5 fresh B-stores. Guarantees xs[(t+1)&1]
//   visible to all waves before A(t+1) reads it.
// - Protocol (proven r7, 14.76ms): self-validating tagged u64 exchange,
//   fire-and-forget publish, merged poll+load, per-wave K-slices, agent
//   atomics. Same-thread same-cell stores ordered by per-location coherence.
// - Sticky 'alive' guard -> loud wrong answer instead of hang.
// ---------------------------------------------------------------------------

#define T_TOT 2056
#define S_SEQ 2048

typedef _Float16 f16x8 __attribute__((ext_vector_type(8)));
typedef float f32x4 __attribute__((ext_vector_type(4)));

// exchange arrays: static device globals (no workspace-size dependency)
__device__ unsigned long long g_st0[8192];  // [64 rows][128 colpair cells]
__device__ unsigned long long g_st1[8192];
__device__ unsigned long long g_pa0[1024];  // [256 ocol][4 b-groups]
__device__ unsigned long long g_pa1[1024];

__global__ void init_ws() {
  const int i = (int)blockIdx.x * 256 + (int)threadIdx.x;  // 8192 threads
  g_st0[i] = 0ull;
  g_st1[i] = 0ull;
  if (i < 1024) { g_pa0[i] = 0ull; g_pa1[i] = 0ull; }
}

#define AL(P) __hip_atomic_load((P), __ATOMIC_RELAXED, __HIP_MEMORY_SCOPE_AGENT)
#define AS(P, V)                                                               \
  __hip_atomic_store((P), (V), __ATOMIC_RELAXED, __HIP_MEMORY_SCOPE_AGENT)

// raw barrier: LDS visibility only -- vm ops (stores/stage) NOT drained.
#define BAR_LGKM                                                               \
  asm volatile("s_waitcnt lgkmcnt(0)" ::: "memory");                           \
  __builtin_amdgcn_s_barrier();                                                \
  __builtin_amdgcn_sched_barrier(0);                                           \
  asm volatile("" ::: "memory");

// raw barrier + vmcnt(5): drains stage loads + previous-phase stores
// (old, ~free) while leaving this phase's 5 fresh publish stores in flight.
#define BAR_LGKM_VM5                                                           \
  asm volatile("s_waitcnt lgkmcnt(0) vmcnt(5)" ::: "memory");                  \
  __builtin_amdgcn_s_barrier();                                                \
  __builtin_amdgcn_sched_barrier(0);                                           \
  asm volatile("" ::: "memory");

// issue the 12 poll loads NOW (early); memory barrier pins the issue point.
#define PHASE_BEGIN(SIN, PIN)                                                  \
    const unsigned long long* pp_ = (PIN) + 4 * tid;                           \
    const unsigned long long* sp_ =                                            \
        (SIN) + (size_t)(16 * b + n) * 128 + (2 * wv) * 16 + kq * 4;           \
    unsigned long long q0_ = AL(pp_ + 0), q1_ = AL(pp_ + 1),                   \
                       q2_ = AL(pp_ + 2), q3_ = AL(pp_ + 3);                   \
    unsigned long long s0_ = AL(sp_ + 0), s1_ = AL(sp_ + 1),                   \
                       s2_ = AL(sp_ + 2), s3_ = AL(sp_ + 3),                   \
                       s4_ = AL(sp_ + 16), s5_ = AL(sp_ + 17),                 \
                       s6_ = AL(sp_ + 18), s7_ = AL(sp_ + 19);                 \
    asm volatile("" ::: "memory");

// spin (first check uses early loads) -> LDS -> lgkm barrier -> centered
// MFMA -> gate -> tagged publish (fire-and-forget) -> end barrier
// (ENDVM selects lgkm-only vs lgkm+vmcnt(5)).
#define PHASE_END(TAGIN, WS, SOUT, POUT, TAGOUT, RAW, ENDVM)                   \
  {                                                                            \
    const unsigned tg_ = (unsigned)(TAGIN);                                    \
    int it_ = 0;                                                               \
    for (;;) {                                                                 \
      const unsigned ok_ =                                                     \
          ((unsigned)(q0_ >> 32) >= tg_) & ((unsigned)(q1_ >> 32) >= tg_) &    \
          ((unsigned)(q2_ >> 32) >= tg_) & ((unsigned)(q3_ >> 32) >= tg_) &    \
          ((unsigned)(s0_ >> 32) >= tg_) & ((unsigned)(s1_ >> 32) >= tg_) &    \
          ((unsigned)(s2_ >> 32) >= tg_) & ((unsigned)(s3_ >> 32) >= tg_) &    \
          ((unsigned)(s4_ >> 32) >= tg_) & ((unsigned)(s5_ >> 32) >= tg_) &    \
          ((unsigned)(s6_ >> 32) >= tg_) & ((unsigned)(s7_ >> 32) >= tg_);     \
      if (ok_) break;                                                          \
      if (!alive || ++it_ > (1 << 16)) { alive = 0; break; }                   \
      q0_ = AL(pp_ + 0); q1_ = AL(pp_ + 1);                                    \
      q2_ = AL(pp_ + 2); q3_ = AL(pp_ + 3);                                    \
      s0_ = AL(sp_ + 0); s1_ = AL(sp_ + 1);                                    \
      s2_ = AL(sp_ + 2); s3_ = AL(sp_ + 3);                                    \
      s4_ = AL(sp_ + 16); s5_ = AL(sp_ + 17);                                  \
      s6_ = AL(sp_ + 18); s7_ = AL(sp_ + 19);                                  \
    }                                                                          \
    const float mean_ = (__uint_as_float((unsigned)q0_) +                      \
                         __uint_as_float((unsigned)q1_) +                      \
                         __uint_as_float((unsigned)q2_) +                      \
                         __uint_as_float((unsigned)q3_)) * 0.015625f;          \
    mean_h[tid] = (_Float16)mean_;                                             \
    {                                                                          \
      unsigned long long* lp_ =                                                \
          (unsigned long long*)&lds_s[n][(2 * wv) * 16 + kq * 4];              \
      lp_[0] = ((unsigned long long)(unsigned)s1_ << 32) | (unsigned)s0_;      \
      lp_[1] = ((unsigned long long)(unsigned)s3_ << 32) | (unsigned)s2_;      \
      lp_[8] = ((unsigned long long)(unsigned)s5_ << 32) | (unsigned)s4_;      \
      lp_[9] = ((unsigned long long)(unsigned)s7_ << 32) | (unsigned)s6_;      \
    }                                                                          \
    BAR_LGKM                                                                   \
    _Pragma("unroll")                                                          \
    for (int kk = 0; kk < 8; ++kk) {                                           \
      const f16x8 sv_ = *(const f16x8*)&lds_s[n][kk * 16 + kq * 4];            \
      const f16x8 mv_ = *(const f16x8*)&mean_h[kk * 32 + kq * 8];              \
      if (kk & 1)                                                              \
        acc1 = __builtin_amdgcn_mfma_f32_16x16x32_f16(sv_ - mv_, (WS)[kk],     \
                                                      acc1, 0, 0, 0);          \
      else                                                                     \
        acc0 = __builtin_amdgcn_mfma_f32_16x16x32_f16(sv_ - mv_, (WS)[kk],     \
                                                      acc0, 0, 0, 0);          \
    }                                                                          \
    float nv_[4], ssum_ = 0.f;                                                 \
    _Pragma("unroll")                                                          \
    for (int r = 0; r < 4; ++r) {                                              \
      const float z = acc0[r] + acc1[r];                                       \
      const float p = __shfl_xor(z, 8);                                        \
      const float z0 = (n < 8) ? z : p;                                        \
      const float z1 = (n < 8) ? p : z;                                        \
      /* branch-free tanh: clamp +-10, (e-1)/(e+1); err << f16 quantization */ \
      const float z1c = fminf(fmaxf(z1, -10.f), 10.f);                         \
      const float e2 = __expf(2.f * z1c);                                      \
      const float th = (e2 - 1.f) * __builtin_amdgcn_rcpf(e2 + 1.f);           \
      const float cv = fminf(fmaxf(z0, 0.f), 6.f) * th;                        \
      const float o = ((RAW)[r] + cv) * 0.5f;                                  \
      (RAW)[r] = o; nv_[r] = o; ssum_ += o;                                    \
    }                                                                          \
    ssum_ += __shfl_xor(ssum_, 16);                                            \
    ssum_ += __shfl_xor(ssum_, 32);                                            \
    _Pragma("unroll")                                                          \
    for (int r = 0; r < 4; ++r) {                                              \
      union { _Float16 h; unsigned short u; } hb_;                             \
      hb_.h = (_Float16)nv_[r];                                                \
      const unsigned pr_ = (unsigned)__shfl_xor((int)hb_.u, 1) & 0xFFFFu;      \
      if ((n & 1) == 0 && n < 8) {                                             \
        const unsigned dw_ = (unsigned)hb_.u | (pr_ << 16);                    \
        AS((SOUT) + (size_t)(16 * b + kq * 4 + r) * 128 + (ocol >> 1),         \
           ((unsigned long long)(unsigned)(TAGOUT) << 32) |                    \
               (unsigned long long)dw_);                                       \
      }                                                                        \
    }                                                                          \
    if (kq == 0 && n < 8)                                                      \
      AS((POUT) + (size_t)ocol * 4 + b,                                        \
         ((unsigned long long)(unsigned)(TAGOUT) << 32) |                      \
             (unsigned long long)__float_as_uint(ssum_));                      \
    if (ENDVM) { BAR_LGKM_VM5 } else { BAR_LGKM }                              \
  }

// stage x(t=TT) into xs[TT&1]: wave wv stages rows wv*4..wv*4+3; one
// global_load_lds per row (64 lanes x 16B = full 1024B row). Zero VGPRs,
// cannot be sunk by the compiler (side-effecting intrinsic).
#define STAGE_X(TT)                                                            \
  if ((TT) < S_SEQ) {                                                          \
    const int bf_ = (TT) & 1;                                                  \
    _Pragma("unroll")                                                          \
    for (int j_ = 0; j_ < 4; ++j_) {                                           \
      const int row_ = wv * 4 + j_;                                            \
      const float* gs_ =                                                       \
          xg + ((size_t)(16 * b + row_) * S_SEQ + (TT)) * 256 + ln * 4;        \
      __builtin_amdgcn_global_load_lds(                                        \
          (const __attribute__((address_space(1))) unsigned*)gs_,              \
          (__attribute__((address_space(3))) unsigned*)&xs[bf_][row_][0],      \
          16, 0, 0);                                                           \
    }                                                                          \
  }

__launch_bounds__(256, 1)
__global__ void rnn_kernel(const float* __restrict__ xg,
                           const float* __restrict__ hs,
                           const float* __restrict__ W0,
                           const float* __restrict__ W1,
                           float* __restrict__ out) {
  const int wgid = (int)blockIdx.x;        // 0..31
  const int b = wgid & 3;                  // batch group: rows 16b..16b+15
  const int c = wgid >> 2;                 // col group: o-cols 32c..32c+31
  const int tid = (int)threadIdx.x;
  const int wv = tid >> 6;                 // wave 0..3
  const int ln = tid & 63;
  const int n = ln & 15;                   // packed col in tile / A-row
  const int kq = ln >> 4;                  // quad 0..3
  const int ocol = c * 32 + wv * 8 + (n & 7);      // owned output column
  const int wrow = (n < 8) ? ocol : (256 + ocol);  // packed W row (z0|z1)

  __shared__ __align__(16) unsigned lds_s[16][132];   // state payload, padded
  __shared__ __align__(16) _Float16 mean_h[256];
  __shared__ __align__(16) float xs[2][16][262];      // x stage, 262-padded

  // ---- preload W fragments (state part + x part) into registers ----
  f16x8 w0s[8], w0x[8], w1s[8], w1x[8];
  float w0pa, w0pb, w1pa, w1pb;
  {
    const float* r0 = W0 + (size_t)wrow * 514;
    const float* r1 = W1 + (size_t)wrow * 514;
#pragma unroll
    for (int kk = 0; kk < 8; ++kk) {
      const int k0 = kk * 32 + kq * 8;
      f16x8 a, bx, a1, bx1;
#pragma unroll
      for (int j = 0; j < 8; ++j) {
        a[j]   = (_Float16)r0[k0 + j];
        bx[j]  = (_Float16)r0[256 + k0 + j];
        a1[j]  = (_Float16)r1[k0 + j];
        bx1[j] = (_Float16)r1[256 + k0 + j];
      }
      w0s[kk] = a; w0x[kk] = bx; w1s[kk] = a1; w1x[kk] = bx1;
    }
    w0pa = r0[512]; w0pb = r0[513];
    w1pa = r1[512]; w1pb = r1[513];
  }

  // ---- raw recurrence state (fp32, register-resident) ----
  float raw0[4], raw1[4];
#pragma unroll
  for (int r = 0; r < 4; ++r) { raw0[r] = hs[ocol]; raw1[r] = hs[256 + ocol]; }

  int alive = 1;

  // ---- init publish: tagged uncentered h0 pairs + tagged partials, tag 1.
  {
    union { _Float16 h; unsigned short u; } e0, e1;
    e0.h = (_Float16)hs[ocol]; e1.h = (_Float16)hs[ocol + 1];
    const unsigned dw = (unsigned)e0.u | ((unsigned)e1.u << 16);
    if ((n & 1) == 0 && n < 8) {
#pragma unroll
      for (int r = 0; r < 4; ++r)
        AS(g_st0 + (size_t)(16 * b + kq * 4 + r) * 128 + (ocol >> 1),
           (1ull << 32) | (unsigned long long)dw);
    }
    if (kq == 0 && n < 8)
      AS(g_pa0 + (size_t)ocol * 4 + b,
         (1ull << 32) |
             (unsigned long long)__float_as_uint(16.f * hs[ocol]));
  }

  // ---- prologue: stage x(0) into xs[0] (one-time full drain is fine) ----
  STAGE_X(0);
  asm volatile("s_waitcnt vmcnt(0)" ::: "memory");
  __syncthreads();

  f16x8 xa[8];
  for (int t = 0; t < T_TOT; ++t) {
    const float pe0 = (float)(t + 1);
    const float pe1 = (pe0 - 1028.5f) * (1.0f / 1028.5f);
    const int have_x = (t < S_SEQ);

    // ---------------- phase A: o1 = (h1 + calc(h0c, s, W0)) * 0.5 ----------
    {
      f32x4 acc0, acc1;
      const float pt = pe0 * w0pa + pe1 * w0pb;
      acc0[0] = pt; acc0[1] = pt; acc0[2] = pt; acc0[3] = pt;
      acc1[0] = 0.f; acc1[1] = 0.f; acc1[2] = 0.f; acc1[3] = 0.f;
      PHASE_BEGIN(g_st0, g_pa0);     // poll loads in flight during x work
      STAGE_X(t + 1);                // async x(t+1) -> LDS, zero VGPR
      if (have_x) {
        const float* xr = &xs[t & 1][n][0];
#pragma unroll
        for (int kk = 0; kk < 8; ++kk) {
          const float2 a0 = *(const float2*)(xr + kk * 32 + kq * 8);
          const float2 a1 = *(const float2*)(xr + kk * 32 + kq * 8 + 2);
          const float2 a2 = *(const float2*)(xr + kk * 32 + kq * 8 + 4);
          const float2 a3 = *(const float2*)(xr + kk * 32 + kq * 8 + 6);
          f16x8 af;
          af[0] = (_Float16)a0.x; af[1] = (_Float16)a0.y;
          af[2] = (_Float16)a1.x; af[3] = (_Float16)a1.y;
          af[4] = (_Float16)a2.x; af[5] = (_Float16)a2.y;
          af[6] = (_Float16)a3.x; af[7] = (_Float16)a3.y;
          xa[kk] = af;
          if (kk & 1)
            acc1 = __builtin_amdgcn_mfma_f32_16x16x32_f16(af, w0x[kk], acc1,
                                                          0, 0, 0);
          else
            acc0 = __builtin_amdgcn_mfma_f32_16x16x32_f16(af, w0x[kk], acc0,
                                                          0, 0, 0);
        }
      }
      PHASE_END(2 * t + 1, w0s, g_st1, g_pa1, 2 * t + 2, raw1, 0);
    }

    // ---------------- phase B: o0 = (h0 + calc(o1c, s, W1)) * 0.5 ----------
    {
      f32x4 acc0, acc1;
      const float pt = pe0 * w1pa + pe1 * w1pb;
      acc0[0] = pt; acc0[1] = pt; acc0[2] = pt; acc0[3] = pt;
      acc1[0] = 0.f; acc1[1] = 0.f; acc1[2] = 0.f; acc1[3] = 0.f;
      PHASE_BEGIN(g_st1, g_pa1);     // poll loads in flight during x-MFMAs
      if (have_x) {
#pragma unroll
        for (int kk = 0; kk < 8; ++kk) {
          if (kk & 1)
            acc1 = __builtin_amdgcn_mfma_f32_16x16x32_f16(xa[kk], w1x[kk],
                                                          acc1, 0, 0, 0);
          else
            acc0 = __builtin_amdgcn_mfma_f32_16x16x32_f16(xa[kk], w1x[kk],
                                                          acc0, 0, 0, 0);
        }
      }
      // B-end barrier drains stage loads (vmcnt(5)) so xs[(t+1)&1] is
      // valid for all waves at A(t+1); fresh B stores stay in flight.
      PHASE_END(2 * t + 2, w1s, g_st0, g_pa0, 2 * t + 3, raw0, 1);
    }
  }

  // ---- final h = [o0 | o1] fp32 ----
  if (n < 8) {
#pragma unroll
    for (int r = 0; r < 4; ++r) {
      const int row = 16 * b + kq * 4 + r;
      out[(size_t)row * 512 + ocol] = raw0[r];
      out[(size_t)row * 512 + 256 + ocol] = raw1[r];
    }
  }
}

#undef STAGE_X
#undef PHASE_END
#undef PHASE_BEGIN
#undef BAR_LGKM_VM5
#undef BAR_LGKM
#undef AS
#undef AL

extern "C" void kernel_launch(void* const* d_in, const int* in_sizes, int n_in,
                              void* d_out, int out_size, void* d_ws, size_t ws_size,
                              hipStream_t stream) {
  (void)in_sizes; (void)n_in; (void)out_size; (void)d_ws; (void)ws_size;
  const float* x  = (const float*)d_in[0];
  const float* hs = (const float*)d_in[1];
  const float* W0 = (const float*)d_in[2];
  const float* W1 = (const float*)d_in[3];
  float* out = (float*)d_out;

  // prologue kernel zeroes the tagged exchange globals (stream-ordered;
  // replayed per graph iteration -> tags reset each run). No workspace use.
  init_ws<<<dim3(32), dim3(256), 0, stream>>>();
  rnn_kernel<<<dim3(32), dim3(256), 0, stream>>>(x, hs, W0, W1, out);
}